// Round 1
// baseline (772.399 us; speedup 1.0000x reference)
//
#include <hip/hip_runtime.h>
#include <math.h>

#define PI_F 3.14159265358979323846f

__constant__ float c_pkva[12] = {
  -0.0144f, 0.0272f, -0.0526f, 0.0972f, -0.193f, 0.63f,
   0.63f, -0.193f, 0.0972f, -0.0526f, 0.0272f, -0.0144f
};

constexpr int ilog2c(int n) { int l = 0; while (n > 1) { n >>= 1; ++l; } return l; }

// LDS bank-conflict-free index remap: pad 1 element per 16.
// phys(i+C) == phys(i) + C + (C>>4) for all offsets C used below (no low-4-bit carry).
constexpr int padof(int n) { return n + (n >> 4); }
__device__ __forceinline__ constexpr int phys(int i) { return i + (i >> 4); }

// Meyer phi lookup table: [0,1024) for N=1024, [1024,1536) N=512,
// [1536,1792) N=256, [1792,1920) N=128. Filled by phi_init_k each launch.
__device__ float g_phi[1920];
constexpr int phi_off(int N) {
  return (N == 1024) ? 0 : (N == 512) ? 1024 : (N == 256) ? 1536 : 1792;
}

__device__ __forceinline__ float phi_dev(int k, int n) {
  int kk = (k < n - k) ? k : (n - k);
  float w = 2.0f * PI_F * (float)kk / (float)n;
  float s = (w - PI_F / 3.0f) * (3.0f / PI_F);
  s = fminf(fmaxf(s, 0.0f), 1.0f);
  float s2 = s * s;
  float beta = s2 * s2 * (35.0f - 84.0f * s + 70.0f * s2 - 20.0f * s2 * s);
  return __cosf(0.5f * PI_F * beta);
}

__global__ void phi_init_k() {
  int i = blockIdx.x * 256 + threadIdx.x;
  if (i < 1024)      g_phi[i] = phi_dev(i, 1024);
  else if (i < 1536) g_phi[i] = phi_dev(i - 1024, 512);
  else if (i < 1792) g_phi[i] = phi_dev(i - 1536, 256);
  else if (i < 1920) g_phi[i] = phi_dev(i - 1792, 128);
}

__device__ __forceinline__ float2 cmul(float2 a, float2 b) {
  return make_float2(a.x * b.x - a.y * b.y, a.x * b.y + a.y * b.x);
}
__device__ __forceinline__ float2 cadd(float2 a, float2 b) { return make_float2(a.x + b.x, a.y + b.y); }
__device__ __forceinline__ float2 csub(float2 a, float2 b) { return make_float2(a.x - b.x, a.y - b.y); }

// ---------------------------------------------------------------------------
// In-LDS Stockham radix-4 FFT core, bank-conflict-free via phys() remap.
// NT = N/4. Optional lead radix-2 when log2(N) odd.
// Caller syncs after filling sbuf[cur] (at phys() indices). Returns final buf.
// ---------------------------------------------------------------------------
template <int N>
__device__ __forceinline__ int fft_core4(float2 (*sbuf)[padof(N)], float dirsign, int tid, int cur) {
  constexpr int LOG2 = ilog2c(N);
  constexpr int NT = N / 4;
  constexpr bool LEAD2 = (LOG2 & 1);
  if constexpr (LEAD2) {
#pragma unroll
    for (int j = tid; j < N / 2; j += NT) {
      float2 v0 = sbuf[cur][phys(j)], v1 = sbuf[cur][phys(j + N / 2)];
      float2 e = cadd(v0, v1), o = csub(v0, v1);
      int p = phys(2 * j);              // phys(2j+1) == phys(2j)+1 (2j even)
      sbuf[cur ^ 1][p]     = e;
      sbuf[cur ^ 1][p + 1] = o;
    }
    cur ^= 1;
    __syncthreads();
  }
  const int pj = phys(tid);
#pragma unroll
  for (int Ns = LEAD2 ? 2 : 1; Ns < N; Ns <<= 2) {
    int j = tid;
    int base = j & (Ns - 1);
    float ang = dirsign * (2.0f * PI_F) * (float)base / (float)(4 * Ns);
    float2 w1; __sincosf(ang, &w1.y, &w1.x);
    float2 w2 = cmul(w1, w1);
    float2 w3 = cmul(w2, w1);
    float2 v0 = sbuf[cur][pj];
    float2 v1 = cmul(sbuf[cur][pj + phys(N / 4)], w1);
    float2 v2 = cmul(sbuf[cur][pj + phys(N / 2)], w2);
    float2 v3 = cmul(sbuf[cur][pj + phys(3 * (N / 4))], w3);
    float2 a0 = cadd(v0, v2), a1 = csub(v0, v2);
    float2 a2 = cadd(v1, v3), a3 = csub(v1, v3);
    float2 r1 = make_float2(-dirsign * a3.y, dirsign * a3.x);
    int idxD = ((j - base) << 2) + base;
    int pD = phys(idxD);                // offsets below stay carry-free
    cur ^= 1;
    sbuf[cur][pD]                                   = cadd(a0, a2);
    sbuf[cur][pD + (Ns + (Ns >> 4))]                = cadd(a1, r1);
    sbuf[cur][pD + (2 * Ns + ((2 * Ns) >> 4))]      = csub(a0, a2);
    sbuf[cur][pD + (3 * Ns + ((3 * Ns) >> 4))]      = csub(a1, r1);
    __syncthreads();
  }
  return cur;
}

// ---------------------------------------------------------------------------
// Batched row FFT. LMODE: 1 = complex load, 2 = complex * Hm mask (table).
// SMODE: 0 = complex store, 1 = real store.
// ---------------------------------------------------------------------------
template <int N, int LMODE, int SMODE>
__global__ void __launch_bounds__(N / 4)
fft_rows_k(const void* __restrict__ vin, void* __restrict__ vout,
           float dirsign, float scale) {
  constexpr int NT = N / 4;
  __shared__ __align__(16) float2 sbuf[2][padof(N)];
  const int tid = threadIdx.x;
  const int row = blockIdx.x;
  const int r = row & (N - 1);

  if (LMODE == 1) {
    const float2* in = (const float2*)vin;
#pragma unroll
    for (int i = tid; i < N; i += NT) {
      float2 v = in[(size_t)row * N + i];
      sbuf[0][phys(i)] = make_float2(v.x * scale, v.y * scale);
    }
  } else {
    const float2* in = (const float2*)vin;
    float pr = g_phi[phi_off(N) + r];
#pragma unroll
    for (int i = tid; i < N; i += NT) {
      float lm = pr * g_phi[phi_off(N) + i];
      float m = sqrtf(fmaxf(1.0f - lm * lm, 0.0f)) * scale;
      float2 v = in[(size_t)row * N + i];
      sbuf[0][phys(i)] = make_float2(v.x * m, v.y * m);
    }
  }
  __syncthreads();

  int cur = fft_core4<N>(sbuf, dirsign, tid, 0);

  if (SMODE == 0) {
    float2* outp = (float2*)vout;
#pragma unroll
    for (int i = tid; i < N; i += NT)
      outp[(size_t)row * N + i] = sbuf[cur][phys(i)];
  } else {
    float* outp = (float*)vout;
#pragma unroll
    for (int i = tid; i < N; i += NT)
      outp[(size_t)row * N + i] = sbuf[cur][phys(i)].x;
  }
}

// ---------------------------------------------------------------------------
// First forward FFT on real input: rows (2r, 2r+1) packed as one complex FFT,
// untangled via Hermitian symmetry.
// ---------------------------------------------------------------------------
template <int N>
__global__ void __launch_bounds__(N / 4)
rfft_pairs_k(const float* __restrict__ in, float2* __restrict__ out) {
  constexpr int NT = N / 4;
  __shared__ __align__(16) float2 sbuf[2][padof(N)];
  const int tid = threadIdx.x;
  const int img = blockIdx.x >> (ilog2c(N) - 1);
  const int r = blockIdx.x & (N / 2 - 1);
  const size_t row0 = (size_t)img * N + 2 * r;
  const float* p0 = in + row0 * N;
  const float* p1 = p0 + N;

#pragma unroll
  for (int i = tid; i < N; i += NT)
    sbuf[0][phys(i)] = make_float2(p0[i], p1[i]);
  __syncthreads();

  int cur = fft_core4<N>(sbuf, -1.0f, tid, 0);

  float2* o0 = out + row0 * N;
  float2* o1 = o0 + N;
#pragma unroll
  for (int i = tid; i < N; i += NT) {
    float2 Z = sbuf[cur][phys(i)];
    float2 Zr = sbuf[cur][phys((N - i) & (N - 1))];
    float2 Zc = make_float2(Zr.x, -Zr.y);
    o0[i] = make_float2(0.5f * (Z.x + Zc.x), 0.5f * (Z.y + Zc.y));
    float2 dd = make_float2(Z.x - Zc.x, Z.y - Zc.y);
    o1[i] = make_float2(0.5f * dd.y, -0.5f * dd.x);
  }
}

// ---------------------------------------------------------------------------
// Fused level-1 column pass + kx-fold. Each block handles columns kx and
// kx+N/2 sequentially: fwd FFT along ky, Lm-masked ky-fold partials kept in
// LDS, Hm mask + inverse FFT stored in place. On the second column the two
// kx partials are summed and written directly to spec2 (replaces fold_rows_k:
// saves 134 MB of HBM round-trip).
// ---------------------------------------------------------------------------
template <int N>
__global__ void __launch_bounds__(N / 4)
fft_col_fold_k(float2* __restrict__ inout, float2* __restrict__ spec2) {
  constexpr int NT = N / 4;
  constexpr int NH = N / 2;
  constexpr int LH = ilog2c(NH);
  __shared__ __align__(16) float2 sbuf[2][padof(N)];
  __shared__ float2 sfold[NH];
  const int tid = threadIdx.x;
  const int img = blockIdx.x >> LH;
  const int kx = blockIdx.x & (NH - 1);
  const float inv = 1.0f / (float)N;

#pragma unroll
  for (int half = 0; half < 2; ++half) {
    const int row = img * N + kx + half * NH;
#pragma unroll
    for (int i = tid; i < N; i += NT)
      sbuf[0][phys(i)] = inout[(size_t)row * N + i];
    __syncthreads();

    int cur = fft_core4<N>(sbuf, -1.0f, tid, 0);

    const float pr = g_phi[phi_off(N) + kx + half * NH];
#pragma unroll
    for (int i = tid; i < NH; i += NT) {
      float2 vA = sbuf[cur][phys(i)];
      float2 vB = sbuf[cur][phys(i + NH)];
      float lmA = pr * g_phi[phi_off(N) + i];
      float lmB = pr * g_phi[phi_off(N) + i + NH];
      float2 fc = make_float2(0.25f * (vA.x * lmA + vB.x * lmB),
                              0.25f * (vA.y * lmA + vB.y * lmB));
      if (half == 0) {
        sfold[i] = fc;                          // same thread re-reads in half 1
      } else {
        float2 acc = sfold[i];
        spec2[((size_t)img << (2 * LH)) + ((size_t)kx << LH) + i] =
            make_float2(acc.x + fc.x, acc.y + fc.y);
      }
      float hmA = sqrtf(fmaxf(1.0f - lmA * lmA, 0.0f)) * inv;
      float hmB = sqrtf(fmaxf(1.0f - lmB * lmB, 0.0f)) * inv;
      sbuf[cur][phys(i)]      = make_float2(vA.x * hmA, vA.y * hmA);
      sbuf[cur][phys(i + NH)] = make_float2(vB.x * hmB, vB.y * hmB);
    }
    __syncthreads();

    cur = fft_core4<N>(sbuf, 1.0f, tid, cur);

#pragma unroll
    for (int i = tid; i < N; i += NT)
      inout[(size_t)row * N + i] = sbuf[cur][phys(i)];
    __syncthreads();  // half 1 reload overwrites sbuf[0] == sbuf[cur]
  }
}

// ---------------------------------------------------------------------------
// Fused: inverse row FFT + first DFB fan split (axis=-1). Conflict-free
// deinterleave: contiguous LDS read, scatter-write to stride-1 cosets.
// ---------------------------------------------------------------------------
template <int N>
__global__ void __launch_bounds__(N / 4)
ifft_fan_k(const float2* __restrict__ in, float* __restrict__ outb,
           float scale, int halfT) {
  constexpr int NT = N / 4;
  constexpr int W2 = N / 2;
  __shared__ __align__(16) float2 sbuf[2][padof(N)];
  const int tid = threadIdx.x;
  const int nr = blockIdx.x;
  const int r = nr & (N - 1);
  const int par = r & 1;
  const float sgn = par ? -1.0f : 1.0f;

#pragma unroll
  for (int i = tid; i < N; i += NT) {
    float2 v = in[(size_t)nr * N + i];
    sbuf[0][phys(i)] = make_float2(v.x * scale, v.y * scale);
  }
  __syncthreads();

  int cur = fft_core4<N>(sbuf, 1.0f, tid, 0);

  float* scratch = (float*)sbuf[cur ^ 1];  // 2*padof(N) floats >= 3*W2
  float* xe = scratch;            // W2 floats
  float* xo = scratch + W2;       // W2 floats
  float* db = scratch + 2 * W2;   // W2 floats
#pragma unroll
  for (int i = tid; i < N; i += NT) {
    float v = sbuf[cur][phys(i)].x;
    int ii = (i - par) & (N - 1);
    if (ii & 1) xo[ii >> 1] = v; else xe[ii >> 1] = v;
  }
  __syncthreads();

  float* outs = outb + (size_t)nr * W2;
  float* outd = outb + halfT + (size_t)nr * W2;
#pragma unroll 2
  for (int j = tid; j < W2; j += NT) {
    float acc = 0.0f;
#pragma unroll
    for (int k = 0; k < 12; k++)
      acc += c_pkva[k] * xe[(j - 6 + k + W2) & (W2 - 1)];
    float dv = sgn * (xo[j] - acc);
    db[j] = dv;
    outd[j] = dv;
  }
  __syncthreads();
#pragma unroll 2
  for (int j = tid; j < W2; j += NT) {
    float acc = 0.0f;
#pragma unroll
    for (int k = 0; k < 12; k++)
      acc += c_pkva[k] * db[(j - 6 + k + W2) & (W2 - 1)];
    outs[j] = sgn * xe[j] + 0.5f * acc;
  }
}

// Batched square transpose (per-image), complex
__global__ void transpose_k(const float2* __restrict__ in,
                            float2* __restrict__ out, int N) {
  __shared__ float2 tile[32][33];
  int img = blockIdx.z;
  size_t base = (size_t)img * N * N;
  int x = blockIdx.x * 32 + threadIdx.x;
  int y0 = blockIdx.y * 32;
  for (int j = threadIdx.y; j < 32; j += 8)
    tile[j][threadIdx.x] = in[base + (size_t)(y0 + j) * N + x];
  __syncthreads();
  int x2 = blockIdx.y * 32 + threadIdx.x;
  int y2 = blockIdx.x * 32;
  for (int j = threadIdx.y; j < 32; j += 8)
    out[base + (size_t)(y2 + j) * N + x2] = tile[threadIdx.x][j];
}

// Frequency-domain decimation by 2 with Lm mask (levels 2/3), table-driven.
__global__ void alias_k(const float2* __restrict__ in, float2* __restrict__ out,
                        int N, int lgN2, int phiOff) {
  int idx = blockIdx.x * 256 + threadIdx.x;
  int N2 = N >> 1;
  int c = idx & (N2 - 1);
  int r = (idx >> lgN2) & (N2 - 1);
  int img = idx >> (2 * lgN2);
  float pr0 = g_phi[phiOff + r], pr1 = g_phi[phiOff + r + N2];
  float pc0 = g_phi[phiOff + c], pc1 = g_phi[phiOff + c + N2];
  size_t base = (size_t)img * N * N;
  float2 v00 = in[base + (size_t)r * N + c];
  float2 v01 = in[base + (size_t)r * N + c + N2];
  float2 v10 = in[base + (size_t)(r + N2) * N + c];
  float2 v11 = in[base + (size_t)(r + N2) * N + c + N2];
  float m00 = pr0 * pc0, m01 = pr0 * pc1, m10 = pr1 * pc0, m11 = pr1 * pc1;
  float2 o;
  o.x = 0.25f * (v00.x * m00 + v01.x * m01 + v10.x * m10 + v11.x * m11);
  o.y = 0.25f * (v00.y * m00 + v01.y * m01 + v10.y * m10 + v11.y * m11);
  out[((size_t)img << (2 * lgN2)) + ((size_t)r << lgN2) + c] = o;
}

// Standalone DFB fan split, axis=-1 (mid-pipeline; W <= 512 here).
__global__ void __launch_bounds__(256)
fs_row_k(const float* __restrict__ x, float* __restrict__ outb,
         int lgH, int lgW, int halfT) {
  __shared__ float xe[512], xo[512], db[512];
  int H = 1 << lgH, W = 1 << lgW, W2 = W >> 1;
  int nr = blockIdx.x;
  int r = nr & (H - 1);
  int par = r & 1;
  float sgn = par ? -1.0f : 1.0f;
  const float* xrow = x + (size_t)nr * W;
  for (int j = threadIdx.x; j < W2; j += 256) {
    xe[j] = sgn * xrow[(2 * j + par) & (W - 1)];
    xo[j] = sgn * xrow[(2 * j + 1 + par) & (W - 1)];
  }
  __syncthreads();
  float* outs = outb + (size_t)nr * W2;
  float* outd = outb + halfT + (size_t)nr * W2;
  for (int j = threadIdx.x; j < W2; j += 256) {
    float acc = 0.0f;
#pragma unroll
    for (int k = 0; k < 12; k++)
      acc += c_pkva[k] * xe[(j - 6 + k + W2) & (W2 - 1)];
    float dv = xo[j] - acc;
    db[j] = dv;
    outd[j] = dv;
  }
  __syncthreads();
  for (int j = threadIdx.x; j < W2; j += 256) {
    float acc = 0.0f;
#pragma unroll
    for (int k = 0; k < 12; k++)
      acc += c_pkva[k] * db[(j - 6 + k + W2) & (W2 - 1)];
    outs[j] = xe[j] + 0.5f * acc;
  }
}

// DFB fan split, axis=-2: d pass.
__global__ void __launch_bounds__(256)
fs_col_d_k(const float* __restrict__ x, float* __restrict__ outb,
           int lgH, int lgW, int halfT) {
  int H = 1 << lgH, W = 1 << lgW, H2 = H >> 1;
  int idx = blockIdx.x * 256 + threadIdx.x;
  int c = idx & (W - 1);
  int i = (idx >> lgW) & (H2 - 1);
  int n = idx >> (lgW + lgH - 1);
  int par = c & 1;
  float sgn = par ? -1.0f : 1.0f;
  const float* xim = x + ((size_t)n << (lgH + lgW));
  float p1 = xim[(((2 * i + 1 + par) & (H - 1)) << lgW) + c];
  float acc = 0.0f;
#pragma unroll
  for (int k = 0; k < 12; k++) {
    int m = (i - 6 + k + H2) & (H2 - 1);
    acc += c_pkva[k] * xim[(((2 * m + par) & (H - 1)) << lgW) + c];
  }
  outb[halfT + idx] = sgn * (p1 - acc);
}

// DFB fan split, axis=-2: s pass.
__global__ void __launch_bounds__(256)
fs_col_s_k(const float* __restrict__ x, float* __restrict__ outb,
           int lgH, int lgW, int halfT) {
  int H = 1 << lgH, W = 1 << lgW, H2 = H >> 1;
  int idx = blockIdx.x * 256 + threadIdx.x;
  int c = idx & (W - 1);
  int i = (idx >> lgW) & (H2 - 1);
  int n = idx >> (lgW + lgH - 1);
  int par = c & 1;
  float sgn = par ? -1.0f : 1.0f;
  const float* xim = x + ((size_t)n << (lgH + lgW));
  float p0 = sgn * xim[(((2 * i + par) & (H - 1)) << lgW) + c];
  float acc = 0.0f;
#pragma unroll
  for (int k = 0; k < 12; k++) {
    int m = (i - 6 + k + H2) & (H2 - 1);
    acc += c_pkva[k] * outb[halfT + ((((n << (lgH - 1)) + m) << lgW) + c)];
  }
  outb[idx] = p0 + 0.5f * acc;
}

__global__ void fill_err_k(float* out) {
  out[threadIdx.x] = 1.0e9f;
}

// ---------------------------------------------------------------------------
extern "C" void kernel_launch(void* const* d_in, const int* in_sizes, int n_in,
                              void* d_out, int out_size, void* d_ws, size_t ws_size,
                              hipStream_t stream) {
  const float* x = (const float*)d_in[0];
  float* out = (float*)d_out;
  char* ws = (char*)d_ws;

  const size_t NEED = 312475648ull;
  if (ws_size < NEED) {
    fill_err_k<<<dim3(1), dim3(256), 0, stream>>>(out);
    return;
  }

  float2* bufA  = (float2*)(ws);
  float2* bufB  = (float2*)(ws + 134217728);
  float2* spec2 = (float2*)(ws + 268435456);
  float2* spec3 = (float2*)(ws + 301989888);
  float2* spec4 = (float2*)(ws + 310378496);

  float* out0 = out;             // 262144
  float* out1 = out + 262144;    // 1048576
  float* out2 = out + 1310720;   // 4194304
  float* out3 = out + 5505024;   // 16777216

  phi_init_k<<<dim3(8), dim3(256), 0, stream>>>();

  // ---- Level 1
  rfft_pairs_k<1024><<<dim3(8192), dim3(256), 0, stream>>>(x, bufA);
  transpose_k<<<dim3(32, 32, 16), dim3(32, 8), 0, stream>>>(bufA, bufB, 1024);
  // fwd col FFT + ky-fold + kx-fold -> spec2 directly; Hm*inverse col FFT in-place
  fft_col_fold_k<1024><<<dim3(8192), dim3(256), 0, stream>>>(bufB, spec2);
  transpose_k<<<dim3(32, 32, 16), dim3(32, 8), 0, stream>>>(bufB, bufA, 1024);
  ifft_fan_k<1024><<<dim3(16384), dim3(256), 0, stream>>>(bufA, (float*)bufB, 1.0f / 1024.0f, 8388608);
  // DFB n=4 remaining stages
  fs_col_d_k<<<dim3(32768), dim3(256), 0, stream>>>((float*)bufB, (float*)bufA, 10, 9, 8388608);
  fs_col_s_k<<<dim3(32768), dim3(256), 0, stream>>>((float*)bufB, (float*)bufA, 10, 9, 8388608);
  fs_row_k  <<<dim3(32768), dim3(256), 0, stream>>>((float*)bufA, (float*)bufB, 9, 9, 8388608);
  fs_col_d_k<<<dim3(32768), dim3(256), 0, stream>>>((float*)bufB, out3, 9, 8, 8388608);
  fs_col_s_k<<<dim3(32768), dim3(256), 0, stream>>>((float*)bufB, out3, 9, 8, 8388608);

  // ---- Level 2
  alias_k<<<dim3(4096), dim3(256), 0, stream>>>(spec2, spec3, 512, 8, phi_off(512));
  fft_rows_k<512, 2, 0><<<dim3(8192), dim3(128), 0, stream>>>((const void*)spec2, (void*)bufA, 1.0f, 1.0f / 512.0f);
  transpose_k<<<dim3(16, 16, 16), dim3(32, 8), 0, stream>>>(bufA, bufB, 512);
  ifft_fan_k<512><<<dim3(8192), dim3(128), 0, stream>>>(bufB, (float*)bufA, 1.0f / 512.0f, 2097152);
  fs_col_d_k<<<dim3(8192),  dim3(256), 0, stream>>>((float*)bufA, (float*)bufB, 9, 8, 2097152);
  fs_col_s_k<<<dim3(8192),  dim3(256), 0, stream>>>((float*)bufA, (float*)bufB, 9, 8, 2097152);
  fs_row_k  <<<dim3(16384), dim3(256), 0, stream>>>((float*)bufB, out2, 8, 8, 2097152);

  // ---- Level 3
  alias_k<<<dim3(1024), dim3(256), 0, stream>>>(spec3, spec4, 256, 7, phi_off(256));
  fft_rows_k<256, 2, 0><<<dim3(4096), dim3(64), 0, stream>>>((const void*)spec3, (void*)bufA, 1.0f, 1.0f / 256.0f);
  transpose_k<<<dim3(8, 8, 16), dim3(32, 8), 0, stream>>>(bufA, bufB, 256);
  ifft_fan_k<256><<<dim3(4096), dim3(64), 0, stream>>>(bufB, (float*)bufA, 1.0f / 256.0f, 524288);
  fs_col_d_k<<<dim3(2048), dim3(256), 0, stream>>>((float*)bufA, out1, 8, 7, 524288);
  fs_col_s_k<<<dim3(2048), dim3(256), 0, stream>>>((float*)bufA, out1, 8, 7, 524288);

  // ---- Final lowpass: out0 = ifft2(X4^T) at 128^2
  fft_rows_k<128, 1, 0><<<dim3(2048), dim3(32), 0, stream>>>((const void*)spec4, (void*)bufA, 1.0f, 1.0f / 128.0f);
  transpose_k<<<dim3(4, 4, 16), dim3(32, 8), 0, stream>>>(bufA, bufB, 128);
  fft_rows_k<128, 1, 1><<<dim3(2048), dim3(32), 0, stream>>>((const void*)bufB, (void*)out0, 1.0f, 1.0f / 128.0f);
}

// Round 2
// 668.503 us; speedup vs baseline: 1.1554x; 1.1554x over previous
//
#include <hip/hip_runtime.h>
#include <math.h>

#define PI_F 3.14159265358979323846f

__constant__ float c_pkva[12] = {
  -0.0144f, 0.0272f, -0.0526f, 0.0972f, -0.193f, 0.63f,
   0.63f, -0.193f, 0.0972f, -0.0526f, 0.0272f, -0.0144f
};

constexpr int ilog2c(int n) { int l = 0; while (n > 1) { n >>= 1; ++l; } return l; }

// Meyer phi lookup table: [0,1024) for N=1024, [1024,1536) N=512,
// [1536,1792) N=256, [1792,1920) N=128. Filled by phi_init_k each launch.
__device__ float g_phi[1920];
constexpr int phi_off(int N) {
  return (N == 1024) ? 0 : (N == 512) ? 1024 : (N == 256) ? 1536 : 1792;
}

__device__ __forceinline__ float phi_dev(int k, int n) {
  int kk = (k < n - k) ? k : (n - k);
  float w = 2.0f * PI_F * (float)kk / (float)n;
  float s = (w - PI_F / 3.0f) * (3.0f / PI_F);
  s = fminf(fmaxf(s, 0.0f), 1.0f);
  float s2 = s * s;
  float beta = s2 * s2 * (35.0f - 84.0f * s + 70.0f * s2 - 20.0f * s2 * s);
  return __cosf(0.5f * PI_F * beta);
}

__global__ void phi_init_k() {
  int i = blockIdx.x * 256 + threadIdx.x;
  if (i < 1024)      g_phi[i] = phi_dev(i, 1024);
  else if (i < 1536) g_phi[i] = phi_dev(i - 1024, 512);
  else if (i < 1792) g_phi[i] = phi_dev(i - 1536, 256);
  else if (i < 1920) g_phi[i] = phi_dev(i - 1792, 128);
}

__device__ __forceinline__ float2 cmul(float2 a, float2 b) {
  return make_float2(a.x * b.x - a.y * b.y, a.x * b.y + a.y * b.x);
}
__device__ __forceinline__ float2 cadd(float2 a, float2 b) { return make_float2(a.x + b.x, a.y + b.y); }
__device__ __forceinline__ float2 csub(float2 a, float2 b) { return make_float2(a.x - b.x, a.y - b.y); }

// ---------------------------------------------------------------------------
// In-LDS Stockham radix-4 FFT core (unpadded — round-0 proven). NT = N/4.
// Optional lead radix-2 when log2(N) odd (conflict-free float4 store).
// Caller syncs after filling sbuf[cur]. Returns final buffer index.
// ---------------------------------------------------------------------------
template <int N>
__device__ __forceinline__ int fft_core4(float2 (*sbuf)[N], float dirsign, int tid, int cur) {
  constexpr int LOG2 = ilog2c(N);
  constexpr int NT = N / 4;
  constexpr bool LEAD2 = (LOG2 & 1);
  if constexpr (LEAD2) {
#pragma unroll
    for (int j = tid; j < N / 2; j += NT) {
      float2 v0 = sbuf[cur][j], v1 = sbuf[cur][j + N / 2];
      float2 e = cadd(v0, v1), o = csub(v0, v1);
      *(float4*)&sbuf[cur ^ 1][2 * j] = make_float4(e.x, e.y, o.x, o.y);
    }
    cur ^= 1;
    __syncthreads();
  }
#pragma unroll
  for (int Ns = LEAD2 ? 2 : 1; Ns < N; Ns <<= 2) {
    int j = tid;
    int base = j & (Ns - 1);
    float ang = dirsign * (2.0f * PI_F) * (float)base / (float)(4 * Ns);
    float2 w1; __sincosf(ang, &w1.y, &w1.x);
    float2 w2 = cmul(w1, w1);
    float2 w3 = cmul(w2, w1);
    float2 v0 = sbuf[cur][j];
    float2 v1 = cmul(sbuf[cur][j + N / 4], w1);
    float2 v2 = cmul(sbuf[cur][j + N / 2], w2);
    float2 v3 = cmul(sbuf[cur][j + 3 * (N / 4)], w3);
    float2 a0 = cadd(v0, v2), a1 = csub(v0, v2);
    float2 a2 = cadd(v1, v3), a3 = csub(v1, v3);
    float2 r1 = make_float2(-dirsign * a3.y, dirsign * a3.x);
    int idxD = ((j - base) << 2) + base;
    cur ^= 1;
    sbuf[cur][idxD]          = cadd(a0, a2);
    sbuf[cur][idxD + Ns]     = cadd(a1, r1);
    sbuf[cur][idxD + 2 * Ns] = csub(a0, a2);
    sbuf[cur][idxD + 3 * Ns] = csub(a1, r1);
    __syncthreads();
  }
  return cur;
}

// ---------------------------------------------------------------------------
// Batched row FFT. LMODE: 1 = complex load, 2 = complex * Hm mask (table).
// SMODE: 0 = complex store, 1 = real store.
// ---------------------------------------------------------------------------
template <int N, int LMODE, int SMODE>
__global__ void __launch_bounds__(N / 4)
fft_rows_k(const void* __restrict__ vin, void* __restrict__ vout,
           float dirsign, float scale) {
  constexpr int NT = N / 4;
  __shared__ __align__(16) float2 sbuf[2][N];
  const int tid = threadIdx.x;
  const int row = blockIdx.x;
  const int r = row & (N - 1);

  if (LMODE == 1) {
    const float2* in = (const float2*)vin;
#pragma unroll
    for (int i = tid; i < N; i += NT) {
      float2 v = in[(size_t)row * N + i];
      sbuf[0][i] = make_float2(v.x * scale, v.y * scale);
    }
  } else {
    const float2* in = (const float2*)vin;
    float pr = g_phi[phi_off(N) + r];
#pragma unroll
    for (int i = tid; i < N; i += NT) {
      float lm = pr * g_phi[phi_off(N) + i];
      float m = sqrtf(fmaxf(1.0f - lm * lm, 0.0f)) * scale;
      float2 v = in[(size_t)row * N + i];
      sbuf[0][i] = make_float2(v.x * m, v.y * m);
    }
  }
  __syncthreads();

  int cur = fft_core4<N>(sbuf, dirsign, tid, 0);

  if (SMODE == 0) {
    float2* outp = (float2*)vout;
#pragma unroll
    for (int i = tid; i < N; i += NT)
      outp[(size_t)row * N + i] = sbuf[cur][i];
  } else {
    float* outp = (float*)vout;
#pragma unroll
    for (int i = tid; i < N; i += NT)
      outp[(size_t)row * N + i] = sbuf[cur][i].x;
  }
}

// ---------------------------------------------------------------------------
// First forward FFT on real input: rows (2r, 2r+1) packed as one complex FFT,
// untangled via Hermitian symmetry. HALF-SPECTRUM output: row spectra of real
// rows satisfy A[N-k] = conj(A[k]), so only kx in [0, N/2] is stored
// (pitch PITCH).
// ---------------------------------------------------------------------------
template <int N, int PITCH>
__global__ void __launch_bounds__(N / 4)
rfft_pairs_half_k(const float* __restrict__ in, float2* __restrict__ out) {
  constexpr int NT = N / 4;
  __shared__ __align__(16) float2 sbuf[2][N];
  const int tid = threadIdx.x;
  const int img = blockIdx.x >> (ilog2c(N) - 1);
  const int r = blockIdx.x & (N / 2 - 1);
  const float* p0 = in + ((size_t)img * N + 2 * r) * N;
  const float* p1 = p0 + N;

#pragma unroll
  for (int i = tid; i < N; i += NT)
    sbuf[0][i] = make_float2(p0[i], p1[i]);
  __syncthreads();

  int cur = fft_core4<N>(sbuf, -1.0f, tid, 0);

  float2* o0 = out + ((size_t)img * N + 2 * r) * PITCH;
  float2* o1 = o0 + PITCH;
#pragma unroll
  for (int i = tid; i <= N / 2; i += NT) {
    float2 Z = sbuf[cur][i];
    float2 Zr = sbuf[cur][(N - i) & (N - 1)];
    float2 Zc = make_float2(Zr.x, -Zr.y);
    o0[i] = make_float2(0.5f * (Z.x + Zc.x), 0.5f * (Z.y + Zc.y));
    float2 dd = make_float2(Z.x - Zc.x, Z.y - Zc.y);
    o1[i] = make_float2(0.5f * dd.y, -0.5f * dd.x);
  }
}

// Rectangular tiled transpose, per-image: in R x C -> out C x R. R, C
// multiples of 32.
__global__ void transpose_rect_k(const float2* __restrict__ in,
                                 float2* __restrict__ out, int R, int C) {
  __shared__ float2 tile[32][33];
  int img = blockIdx.z;
  size_t base = (size_t)img * R * C;
  int c = blockIdx.x * 32 + threadIdx.x;
  int r0 = blockIdx.y * 32;
  for (int j = threadIdx.y; j < 32; j += 8)
    tile[j][threadIdx.x] = in[base + (size_t)(r0 + j) * C + c];
  __syncthreads();
  int r = blockIdx.y * 32 + threadIdx.x;
  int c0 = blockIdx.x * 32;
  for (int j = threadIdx.y; j < 32; j += 8)
    out[base + (size_t)(c0 + j) * R + r] = tile[threadIdx.x][j];
}

// ---------------------------------------------------------------------------
// Level-1 column pass, HALF SPECTRUM: one block per kx in [0, N/2].
// Fwd FFT along ky, Lm-masked ky-fold written to foldb, Hm mask + inverse
// FFT stored in place.
// ---------------------------------------------------------------------------
template <int N, int PITCH>
__global__ void __launch_bounds__(N / 4)
fft_col_half_k(float2* __restrict__ inout, float2* __restrict__ foldb) {
  constexpr int NT = N / 4;
  constexpr int NH = N / 2;
  __shared__ __align__(16) float2 sbuf[2][N];
  const int tid = threadIdx.x;
  const int kx = blockIdx.x;   // 0..N/2 inclusive
  const int img = blockIdx.y;
  float2* rowp = inout + ((size_t)img * PITCH + kx) * N;

#pragma unroll
  for (int i = tid; i < N; i += NT)
    sbuf[0][i] = rowp[i];
  __syncthreads();

  int cur = fft_core4<N>(sbuf, -1.0f, tid, 0);

  const float pr = g_phi[phi_off(N) + kx];
  const float inv = 1.0f / (float)N;
  float2* fp = foldb + ((size_t)img * (NH + 1) + kx) * NH;
#pragma unroll
  for (int i = tid; i < NH; i += NT) {
    float2 vA = sbuf[cur][i];
    float2 vB = sbuf[cur][i + NH];
    float lmA = pr * g_phi[phi_off(N) + i];
    float lmB = pr * g_phi[phi_off(N) + i + NH];
    fp[i] = make_float2(0.25f * (vA.x * lmA + vB.x * lmB),
                        0.25f * (vA.y * lmA + vB.y * lmB));
    float hmA = sqrtf(fmaxf(1.0f - lmA * lmA, 0.0f)) * inv;
    float hmB = sqrtf(fmaxf(1.0f - lmB * lmB, 0.0f)) * inv;
    sbuf[cur][i]      = make_float2(vA.x * hmA, vA.y * hmA);
    sbuf[cur][i + NH] = make_float2(vB.x * hmB, vB.y * hmB);
  }
  __syncthreads();

  cur = fft_core4<N>(sbuf, 1.0f, tid, cur);

#pragma unroll
  for (int i = tid; i < N; i += NT)
    rowp[i] = sbuf[cur][i];
}

// kx-fold from the half-spectrum fold buffer:
// spec2[r][c] = fold[r][c] + conj(fold[512-r][(512-c) mod 512])
// (uses fold_{kx+512}[c] = conj(fold_{512-kx}[(512-c) mod 512]) from the
//  2D Hermitian symmetry of the real input and mask evenness).
__global__ void fold_combine_k(const float2* __restrict__ fold,
                               float2* __restrict__ spec2) {
  int idx = blockIdx.x * 256 + threadIdx.x;
  int c = idx & 511;
  int r = (idx >> 9) & 511;
  int img = idx >> 18;
  const float2* fb = fold + (size_t)img * (513 * 512);
  float2 a = fb[(size_t)r * 512 + c];
  float2 b = fb[(size_t)(512 - r) * 512 + ((512 - c) & 511)];
  spec2[((size_t)img << 18) + ((size_t)r << 9) + c] =
      make_float2(a.x + b.x, a.y - b.y);
}

// ---------------------------------------------------------------------------
// Level-1 fused inverse row FFT + first DFB fan split, TWO ROWS PER BLOCK:
// rows of Z over kx are conjugate-symmetric (Z[N-kx,y] = conj(Z[kx,y])), so
// rows y0=2q (re) and y1=2q+1 (im) are packed into one complex inverse FFT
// built from the stored half-spectrum.
// ---------------------------------------------------------------------------
template <int N, int PITCH>
__global__ void __launch_bounds__(N / 4)
ifft_fan_pair_k(const float2* __restrict__ in, float* __restrict__ outb,
                float scale, int halfT) {
  constexpr int NT = N / 4;
  constexpr int W2 = N / 2;
  __shared__ __align__(16) float2 sbuf[2][N];
  const int tid = threadIdx.x;
  const int img = blockIdx.x >> (ilog2c(N) - 1);
  const int q = blockIdx.x & (N / 2 - 1);
  const int y0 = 2 * q;
  const float2* inA = in + ((size_t)img * N + y0) * PITCH;
  const float2* inB = inA + PITCH;

#pragma unroll
  for (int i = tid; i <= W2; i += NT) {
    float2 a = inA[i], b = inB[i];
    sbuf[0][i] = make_float2((a.x - b.y) * scale, (a.y + b.x) * scale);
  }
#pragma unroll
  for (int i = tid; i < W2 - 1; i += NT) {
    int m = W2 - 1 - i;                  // source index: 511..1
    float2 a = inA[m], b = inB[m];
    sbuf[0][W2 + 1 + i] = make_float2((a.x + b.y) * scale, (b.x - a.y) * scale);
  }
  __syncthreads();

  int cur = fft_core4<N>(sbuf, 1.0f, tid, 0);

  float* scratch = (float*)sbuf[cur ^ 1];
  float* xe = scratch;            // W2 floats
  float* xo = scratch + W2;       // W2 floats
  float* db = scratch + 2 * W2;   // W2 floats
  const size_t rbase = ((size_t)img * N + y0) * W2;

  for (int sub = 0; sub < 2; ++sub) {
    const int par = sub;                 // y0 even, y1 odd
    const float sgn = par ? -1.0f : 1.0f;
#pragma unroll
    for (int i = tid; i < N; i += NT) {
      float v = par ? sbuf[cur][i].y : sbuf[cur][i].x;
      int ii = (i - par) & (N - 1);
      if (ii & 1) xo[ii >> 1] = v; else xe[ii >> 1] = v;
    }
    __syncthreads();

    float* outs = outb + rbase + (size_t)sub * W2;
    float* outd = outb + halfT + rbase + (size_t)sub * W2;
#pragma unroll 2
    for (int j = tid; j < W2; j += NT) {
      float acc = 0.0f;
#pragma unroll
      for (int k = 0; k < 12; k++)
        acc += c_pkva[k] * xe[(j - 6 + k + W2) & (W2 - 1)];
      float dv = sgn * (xo[j] - acc);
      db[j] = dv;
      outd[j] = dv;
    }
    __syncthreads();
#pragma unroll 2
    for (int j = tid; j < W2; j += NT) {
      float acc = 0.0f;
#pragma unroll
      for (int k = 0; k < 12; k++)
        acc += c_pkva[k] * db[(j - 6 + k + W2) & (W2 - 1)];
      outs[j] = sgn * xe[j] + 0.5f * acc;
    }
    __syncthreads();
  }
}

// ---------------------------------------------------------------------------
// Fused: inverse row FFT + first DFB fan split (axis=-1). Used at levels 2/3.
// ---------------------------------------------------------------------------
template <int N>
__global__ void __launch_bounds__(N / 4)
ifft_fan_k(const float2* __restrict__ in, float* __restrict__ outb,
           float scale, int halfT) {
  constexpr int NT = N / 4;
  constexpr int W2 = N / 2;
  __shared__ __align__(16) float2 sbuf[2][N];
  const int tid = threadIdx.x;
  const int nr = blockIdx.x;
  const int r = nr & (N - 1);
  const int par = r & 1;
  const float sgn = par ? -1.0f : 1.0f;

#pragma unroll
  for (int i = tid; i < N; i += NT) {
    float2 v = in[(size_t)nr * N + i];
    sbuf[0][i] = make_float2(v.x * scale, v.y * scale);
  }
  __syncthreads();

  int cur = fft_core4<N>(sbuf, 1.0f, tid, 0);

  float* scratch = (float*)sbuf[cur ^ 1];
  float* xe = scratch;            // W2 floats
  float* xo = scratch + W2;       // W2 floats
  float* db = scratch + 2 * W2;   // W2 floats
#pragma unroll
  for (int i = tid; i < N; i += NT) {
    float v = sbuf[cur][i].x;
    int ii = (i - par) & (N - 1);
    if (ii & 1) xo[ii >> 1] = v; else xe[ii >> 1] = v;
  }
  __syncthreads();

  float* outs = outb + (size_t)nr * W2;
  float* outd = outb + halfT + (size_t)nr * W2;
#pragma unroll 2
  for (int j = tid; j < W2; j += NT) {
    float acc = 0.0f;
#pragma unroll
    for (int k = 0; k < 12; k++)
      acc += c_pkva[k] * xe[(j - 6 + k + W2) & (W2 - 1)];
    float dv = sgn * (xo[j] - acc);
    db[j] = dv;
    outd[j] = dv;
  }
  __syncthreads();
#pragma unroll 2
  for (int j = tid; j < W2; j += NT) {
    float acc = 0.0f;
#pragma unroll
    for (int k = 0; k < 12; k++)
      acc += c_pkva[k] * db[(j - 6 + k + W2) & (W2 - 1)];
    outs[j] = sgn * xe[j] + 0.5f * acc;
  }
}

// Batched square transpose (per-image), complex
__global__ void transpose_k(const float2* __restrict__ in,
                            float2* __restrict__ out, int N) {
  __shared__ float2 tile[32][33];
  int img = blockIdx.z;
  size_t base = (size_t)img * N * N;
  int x = blockIdx.x * 32 + threadIdx.x;
  int y0 = blockIdx.y * 32;
  for (int j = threadIdx.y; j < 32; j += 8)
    tile[j][threadIdx.x] = in[base + (size_t)(y0 + j) * N + x];
  __syncthreads();
  int x2 = blockIdx.y * 32 + threadIdx.x;
  int y2 = blockIdx.x * 32;
  for (int j = threadIdx.y; j < 32; j += 8)
    out[base + (size_t)(y2 + j) * N + x2] = tile[threadIdx.x][j];
}

// Frequency-domain decimation by 2 with Lm mask (levels 2/3), table-driven.
__global__ void alias_k(const float2* __restrict__ in, float2* __restrict__ out,
                        int N, int lgN2, int phiOff) {
  int idx = blockIdx.x * 256 + threadIdx.x;
  int N2 = N >> 1;
  int c = idx & (N2 - 1);
  int r = (idx >> lgN2) & (N2 - 1);
  int img = idx >> (2 * lgN2);
  float pr0 = g_phi[phiOff + r], pr1 = g_phi[phiOff + r + N2];
  float pc0 = g_phi[phiOff + c], pc1 = g_phi[phiOff + c + N2];
  size_t base = (size_t)img * N * N;
  float2 v00 = in[base + (size_t)r * N + c];
  float2 v01 = in[base + (size_t)r * N + c + N2];
  float2 v10 = in[base + (size_t)(r + N2) * N + c];
  float2 v11 = in[base + (size_t)(r + N2) * N + c + N2];
  float m00 = pr0 * pc0, m01 = pr0 * pc1, m10 = pr1 * pc0, m11 = pr1 * pc1;
  float2 o;
  o.x = 0.25f * (v00.x * m00 + v01.x * m01 + v10.x * m10 + v11.x * m11);
  o.y = 0.25f * (v00.y * m00 + v01.y * m01 + v10.y * m10 + v11.y * m11);
  out[((size_t)img << (2 * lgN2)) + ((size_t)r << lgN2) + c] = o;
}

// Standalone DFB fan split, axis=-1 (mid-pipeline; W <= 512 here).
__global__ void __launch_bounds__(256)
fs_row_k(const float* __restrict__ x, float* __restrict__ outb,
         int lgH, int lgW, int halfT) {
  __shared__ float xe[512], xo[512], db[512];
  int H = 1 << lgH, W = 1 << lgW, W2 = W >> 1;
  int nr = blockIdx.x;
  int r = nr & (H - 1);
  int par = r & 1;
  float sgn = par ? -1.0f : 1.0f;
  const float* xrow = x + (size_t)nr * W;
  for (int j = threadIdx.x; j < W2; j += 256) {
    xe[j] = sgn * xrow[(2 * j + par) & (W - 1)];
    xo[j] = sgn * xrow[(2 * j + 1 + par) & (W - 1)];
  }
  __syncthreads();
  float* outs = outb + (size_t)nr * W2;
  float* outd = outb + halfT + (size_t)nr * W2;
  for (int j = threadIdx.x; j < W2; j += 256) {
    float acc = 0.0f;
#pragma unroll
    for (int k = 0; k < 12; k++)
      acc += c_pkva[k] * xe[(j - 6 + k + W2) & (W2 - 1)];
    float dv = xo[j] - acc;
    db[j] = dv;
    outd[j] = dv;
  }
  __syncthreads();
  for (int j = threadIdx.x; j < W2; j += 256) {
    float acc = 0.0f;
#pragma unroll
    for (int k = 0; k < 12; k++)
      acc += c_pkva[k] * db[(j - 6 + k + W2) & (W2 - 1)];
    outs[j] = xe[j] + 0.5f * acc;
  }
}

// DFB fan split, axis=-2: d pass.
__global__ void __launch_bounds__(256)
fs_col_d_k(const float* __restrict__ x, float* __restrict__ outb,
           int lgH, int lgW, int halfT) {
  int H = 1 << lgH, W = 1 << lgW, H2 = H >> 1;
  int idx = blockIdx.x * 256 + threadIdx.x;
  int c = idx & (W - 1);
  int i = (idx >> lgW) & (H2 - 1);
  int n = idx >> (lgW + lgH - 1);
  int par = c & 1;
  float sgn = par ? -1.0f : 1.0f;
  const float* xim = x + ((size_t)n << (lgH + lgW));
  float p1 = xim[(((2 * i + 1 + par) & (H - 1)) << lgW) + c];
  float acc = 0.0f;
#pragma unroll
  for (int k = 0; k < 12; k++) {
    int m = (i - 6 + k + H2) & (H2 - 1);
    acc += c_pkva[k] * xim[(((2 * m + par) & (H - 1)) << lgW) + c];
  }
  outb[halfT + idx] = sgn * (p1 - acc);
}

// DFB fan split, axis=-2: s pass.
__global__ void __launch_bounds__(256)
fs_col_s_k(const float* __restrict__ x, float* __restrict__ outb,
           int lgH, int lgW, int halfT) {
  int H = 1 << lgH, W = 1 << lgW, H2 = H >> 1;
  int idx = blockIdx.x * 256 + threadIdx.x;
  int c = idx & (W - 1);
  int i = (idx >> lgW) & (H2 - 1);
  int n = idx >> (lgW + lgH - 1);
  int par = c & 1;
  float sgn = par ? -1.0f : 1.0f;
  const float* xim = x + ((size_t)n << (lgH + lgW));
  float p0 = sgn * xim[(((2 * i + par) & (H - 1)) << lgW) + c];
  float acc = 0.0f;
#pragma unroll
  for (int k = 0; k < 12; k++) {
    int m = (i - 6 + k + H2) & (H2 - 1);
    acc += c_pkva[k] * outb[halfT + ((((n << (lgH - 1)) + m) << lgW) + c)];
  }
  outb[idx] = p0 + 0.5f * acc;
}

__global__ void fill_err_k(float* out) {
  out[threadIdx.x] = 1.0e9f;
}

// ---------------------------------------------------------------------------
extern "C" void kernel_launch(void* const* d_in, const int* in_sizes, int n_in,
                              void* d_out, int out_size, void* d_ws, size_t ws_size,
                              hipStream_t stream) {
  const float* x = (const float*)d_in[0];
  float* out = (float*)d_out;
  char* ws = (char*)d_ws;

  // Half-spectrum pitch for the kx dimension at level 1.
  // 544 = 17*32 (multiple of 32 for tiled rect transpose), holds kx in [0,512].
  const size_t NEED = 220266496ull;
  if (ws_size < NEED) {
    fill_err_k<<<dim3(1), dim3(256), 0, stream>>>(out);
    return;
  }

  float2* bufA  = (float2*)(ws);                 // 16*1024*544*8 = 71303168
  float2* bufB  = (float2*)(ws + 71303168);      // 71303168
  float2* foldb = (float2*)(ws + 142606336);     // 16*513*512*8 = 33619968
  float2* spec2 = (float2*)(ws + 176226304);     // 33554432
  float2* spec3 = (float2*)(ws + 209780736);     // 8388608
  float2* spec4 = (float2*)(ws + 218169344);     // 2097152

  float* out0 = out;             // 262144
  float* out1 = out + 262144;    // 1048576
  float* out2 = out + 1310720;   // 4194304
  float* out3 = out + 5505024;   // 16777216

  phi_init_k<<<dim3(8), dim3(256), 0, stream>>>();

  // ---- Level 1 (half-spectrum in kx)
  rfft_pairs_half_k<1024, 544><<<dim3(8192), dim3(256), 0, stream>>>(x, bufA);
  // bufA [img][y][kx<=512] (1024 x 544) -> bufB [img][kx][y] (544 x 1024)
  transpose_rect_k<<<dim3(17, 32, 16), dim3(32, 8), 0, stream>>>(bufA, bufB, 1024, 544);
  fft_col_half_k<1024, 544><<<dim3(513, 16), dim3(256), 0, stream>>>(bufB, foldb);
  fold_combine_k<<<dim3(16384), dim3(256), 0, stream>>>(foldb, spec2);
  // bufB (544 x 1024) -> bufA [img][y][kx] (1024 x 544)
  transpose_rect_k<<<dim3(32, 17, 16), dim3(32, 8), 0, stream>>>(bufB, bufA, 544, 1024);
  ifft_fan_pair_k<1024, 544><<<dim3(8192), dim3(256), 0, stream>>>(bufA, (float*)bufB, 1.0f / 1024.0f, 8388608);
  // DFB n=4 remaining stages
  fs_col_d_k<<<dim3(32768), dim3(256), 0, stream>>>((float*)bufB, (float*)bufA, 10, 9, 8388608);
  fs_col_s_k<<<dim3(32768), dim3(256), 0, stream>>>((float*)bufB, (float*)bufA, 10, 9, 8388608);
  fs_row_k  <<<dim3(32768), dim3(256), 0, stream>>>((float*)bufA, (float*)bufB, 9, 9, 8388608);
  fs_col_d_k<<<dim3(32768), dim3(256), 0, stream>>>((float*)bufB, out3, 9, 8, 8388608);
  fs_col_s_k<<<dim3(32768), dim3(256), 0, stream>>>((float*)bufB, out3, 9, 8, 8388608);

  // ---- Level 2
  alias_k<<<dim3(4096), dim3(256), 0, stream>>>(spec2, spec3, 512, 8, phi_off(512));
  fft_rows_k<512, 2, 0><<<dim3(8192), dim3(128), 0, stream>>>((const void*)spec2, (void*)bufA, 1.0f, 1.0f / 512.0f);
  transpose_k<<<dim3(16, 16, 16), dim3(32, 8), 0, stream>>>(bufA, bufB, 512);
  ifft_fan_k<512><<<dim3(8192), dim3(128), 0, stream>>>(bufB, (float*)bufA, 1.0f / 512.0f, 2097152);
  fs_col_d_k<<<dim3(8192),  dim3(256), 0, stream>>>((float*)bufA, (float*)bufB, 9, 8, 2097152);
  fs_col_s_k<<<dim3(8192),  dim3(256), 0, stream>>>((float*)bufA, (float*)bufB, 9, 8, 2097152);
  fs_row_k  <<<dim3(16384), dim3(256), 0, stream>>>((float*)bufB, out2, 8, 8, 2097152);

  // ---- Level 3
  alias_k<<<dim3(1024), dim3(256), 0, stream>>>(spec3, spec4, 256, 7, phi_off(256));
  fft_rows_k<256, 2, 0><<<dim3(4096), dim3(64), 0, stream>>>((const void*)spec3, (void*)bufA, 1.0f, 1.0f / 256.0f);
  transpose_k<<<dim3(8, 8, 16), dim3(32, 8), 0, stream>>>(bufA, bufB, 256);
  ifft_fan_k<256><<<dim3(4096), dim3(64), 0, stream>>>(bufB, (float*)bufA, 1.0f / 256.0f, 524288);
  fs_col_d_k<<<dim3(2048), dim3(256), 0, stream>>>((float*)bufA, out1, 8, 7, 524288);
  fs_col_s_k<<<dim3(2048), dim3(256), 0, stream>>>((float*)bufA, out1, 8, 7, 524288);

  // ---- Final lowpass: out0 = ifft2(X4^T) at 128^2
  fft_rows_k<128, 1, 0><<<dim3(2048), dim3(32), 0, stream>>>((const void*)spec4, (void*)bufA, 1.0f, 1.0f / 128.0f);
  transpose_k<<<dim3(4, 4, 16), dim3(32, 8), 0, stream>>>(bufA, bufB, 128);
  fft_rows_k<128, 1, 1><<<dim3(2048), dim3(32), 0, stream>>>((const void*)bufB, (void*)out0, 1.0f, 1.0f / 128.0f);
}

// Round 3
// 495.550 us; speedup vs baseline: 1.5587x; 1.3490x over previous
//
#include <hip/hip_runtime.h>
#include <math.h>

#define PI_F 3.14159265358979323846f

__constant__ float c_pkva[12] = {
  -0.0144f, 0.0272f, -0.0526f, 0.0972f, -0.193f, 0.63f,
   0.63f, -0.193f, 0.0972f, -0.0526f, 0.0272f, -0.0144f
};

constexpr int ilog2c(int n) { int l = 0; while (n > 1) { n >>= 1; ++l; } return l; }

// Meyer phi lookup table: [0,1024) for N=1024, [1024,1536) N=512,
// [1536,1792) N=256, [1792,1920) N=128. Filled by phi_init_k each launch.
__device__ float g_phi[1920];
constexpr int phi_off(int N) {
  return (N == 1024) ? 0 : (N == 512) ? 1024 : (N == 256) ? 1536 : 1792;
}

__device__ __forceinline__ float phi_dev(int k, int n) {
  int kk = (k < n - k) ? k : (n - k);
  float w = 2.0f * PI_F * (float)kk / (float)n;
  float s = (w - PI_F / 3.0f) * (3.0f / PI_F);
  s = fminf(fmaxf(s, 0.0f), 1.0f);
  float s2 = s * s;
  float beta = s2 * s2 * (35.0f - 84.0f * s + 70.0f * s2 - 20.0f * s2 * s);
  return __cosf(0.5f * PI_F * beta);
}

__global__ void phi_init_k() {
  int i = blockIdx.x * 256 + threadIdx.x;
  if (i < 1024)      g_phi[i] = phi_dev(i, 1024);
  else if (i < 1536) g_phi[i] = phi_dev(i - 1024, 512);
  else if (i < 1792) g_phi[i] = phi_dev(i - 1536, 256);
  else if (i < 1920) g_phi[i] = phi_dev(i - 1792, 128);
}

__device__ __forceinline__ float2 cmul(float2 a, float2 b) {
  return make_float2(a.x * b.x - a.y * b.y, a.x * b.y + a.y * b.x);
}
__device__ __forceinline__ float2 cadd(float2 a, float2 b) { return make_float2(a.x + b.x, a.y + b.y); }
__device__ __forceinline__ float2 csub(float2 a, float2 b) { return make_float2(a.x - b.x, a.y - b.y); }

// ---------------------------------------------------------------------------
// In-LDS Stockham radix-4 FFT core (unpadded — round-0 proven). NT = N/4.
// Optional lead radix-2 when log2(N) odd (conflict-free float4 store).
// Caller syncs after filling sbuf[cur]. Returns final buffer index.
// ---------------------------------------------------------------------------
template <int N>
__device__ __forceinline__ int fft_core4(float2 (*sbuf)[N], float dirsign, int tid, int cur) {
  constexpr int LOG2 = ilog2c(N);
  constexpr int NT = N / 4;
  constexpr bool LEAD2 = (LOG2 & 1);
  if constexpr (LEAD2) {
#pragma unroll
    for (int j = tid; j < N / 2; j += NT) {
      float2 v0 = sbuf[cur][j], v1 = sbuf[cur][j + N / 2];
      float2 e = cadd(v0, v1), o = csub(v0, v1);
      *(float4*)&sbuf[cur ^ 1][2 * j] = make_float4(e.x, e.y, o.x, o.y);
    }
    cur ^= 1;
    __syncthreads();
  }
#pragma unroll
  for (int Ns = LEAD2 ? 2 : 1; Ns < N; Ns <<= 2) {
    int j = tid;
    int base = j & (Ns - 1);
    float ang = dirsign * (2.0f * PI_F) * (float)base / (float)(4 * Ns);
    float2 w1; __sincosf(ang, &w1.y, &w1.x);
    float2 w2 = cmul(w1, w1);
    float2 w3 = cmul(w2, w1);
    float2 v0 = sbuf[cur][j];
    float2 v1 = cmul(sbuf[cur][j + N / 4], w1);
    float2 v2 = cmul(sbuf[cur][j + N / 2], w2);
    float2 v3 = cmul(sbuf[cur][j + 3 * (N / 4)], w3);
    float2 a0 = cadd(v0, v2), a1 = csub(v0, v2);
    float2 a2 = cadd(v1, v3), a3 = csub(v1, v3);
    float2 r1 = make_float2(-dirsign * a3.y, dirsign * a3.x);
    int idxD = ((j - base) << 2) + base;
    cur ^= 1;
    sbuf[cur][idxD]          = cadd(a0, a2);
    sbuf[cur][idxD + Ns]     = cadd(a1, r1);
    sbuf[cur][idxD + 2 * Ns] = csub(a0, a2);
    sbuf[cur][idxD + 3 * Ns] = csub(a1, r1);
    __syncthreads();
  }
  return cur;
}

// ---------------------------------------------------------------------------
// Batched row FFT. LMODE: 1 = complex load, 2 = complex * Hm mask (table).
// SMODE: 0 = complex store, 1 = real store.
// ---------------------------------------------------------------------------
template <int N, int LMODE, int SMODE>
__global__ void __launch_bounds__(N / 4)
fft_rows_k(const void* __restrict__ vin, void* __restrict__ vout,
           float dirsign, float scale) {
  constexpr int NT = N / 4;
  __shared__ __align__(16) float2 sbuf[2][N];
  const int tid = threadIdx.x;
  const int row = blockIdx.x;
  const int r = row & (N - 1);

  if (LMODE == 1) {
    const float2* in = (const float2*)vin;
#pragma unroll
    for (int i = tid; i < N; i += NT) {
      float2 v = in[(size_t)row * N + i];
      sbuf[0][i] = make_float2(v.x * scale, v.y * scale);
    }
  } else {
    const float2* in = (const float2*)vin;
    float pr = g_phi[phi_off(N) + r];
#pragma unroll
    for (int i = tid; i < N; i += NT) {
      float lm = pr * g_phi[phi_off(N) + i];
      float m = sqrtf(fmaxf(1.0f - lm * lm, 0.0f)) * scale;
      float2 v = in[(size_t)row * N + i];
      sbuf[0][i] = make_float2(v.x * m, v.y * m);
    }
  }
  __syncthreads();

  int cur = fft_core4<N>(sbuf, dirsign, tid, 0);

  if (SMODE == 0) {
    float2* outp = (float2*)vout;
#pragma unroll
    for (int i = tid; i < N; i += NT)
      outp[(size_t)row * N + i] = sbuf[cur][i];
  } else {
    float* outp = (float*)vout;
#pragma unroll
    for (int i = tid; i < N; i += NT)
      outp[(size_t)row * N + i] = sbuf[cur][i].x;
  }
}

// ---------------------------------------------------------------------------
// First forward FFT on real input: rows (2r, 2r+1) packed as one complex FFT,
// untangled via Hermitian symmetry. HALF-SPECTRUM output: row spectra of real
// rows satisfy A[N-k] = conj(A[k]), so only kx in [0, N/2] is stored
// (pitch PITCH).
// ---------------------------------------------------------------------------
template <int N, int PITCH>
__global__ void __launch_bounds__(N / 4)
rfft_pairs_half_k(const float* __restrict__ in, float2* __restrict__ out) {
  constexpr int NT = N / 4;
  __shared__ __align__(16) float2 sbuf[2][N];
  const int tid = threadIdx.x;
  const int img = blockIdx.x >> (ilog2c(N) - 1);
  const int r = blockIdx.x & (N / 2 - 1);
  const float* p0 = in + ((size_t)img * N + 2 * r) * N;
  const float* p1 = p0 + N;

#pragma unroll
  for (int i = tid; i < N; i += NT)
    sbuf[0][i] = make_float2(p0[i], p1[i]);
  __syncthreads();

  int cur = fft_core4<N>(sbuf, -1.0f, tid, 0);

  float2* o0 = out + ((size_t)img * N + 2 * r) * PITCH;
  float2* o1 = o0 + PITCH;
#pragma unroll
  for (int i = tid; i <= N / 2; i += NT) {
    float2 Z = sbuf[cur][i];
    float2 Zr = sbuf[cur][(N - i) & (N - 1)];
    float2 Zc = make_float2(Zr.x, -Zr.y);
    o0[i] = make_float2(0.5f * (Z.x + Zc.x), 0.5f * (Z.y + Zc.y));
    float2 dd = make_float2(Z.x - Zc.x, Z.y - Zc.y);
    o1[i] = make_float2(0.5f * dd.y, -0.5f * dd.x);
  }
}

// Rectangular tiled transpose, per-image: in R x C -> out C x R. R, C
// multiples of 32.
__global__ void transpose_rect_k(const float2* __restrict__ in,
                                 float2* __restrict__ out, int R, int C) {
  __shared__ float2 tile[32][33];
  int img = blockIdx.z;
  size_t base = (size_t)img * R * C;
  int c = blockIdx.x * 32 + threadIdx.x;
  int r0 = blockIdx.y * 32;
  for (int j = threadIdx.y; j < 32; j += 8)
    tile[j][threadIdx.x] = in[base + (size_t)(r0 + j) * C + c];
  __syncthreads();
  int r = blockIdx.y * 32 + threadIdx.x;
  int c0 = blockIdx.x * 32;
  for (int j = threadIdx.y; j < 32; j += 8)
    out[base + (size_t)(c0 + j) * R + r] = tile[threadIdx.x][j];
}

// ---------------------------------------------------------------------------
// Level-1 column pass, HALF SPECTRUM: one block per kx in [0, N/2].
// Fwd FFT along ky, Lm-masked ky-fold written to foldb, Hm mask + inverse
// FFT stored in place.
// ---------------------------------------------------------------------------
template <int N, int PITCH>
__global__ void __launch_bounds__(N / 4)
fft_col_half_k(float2* __restrict__ inout, float2* __restrict__ foldb) {
  constexpr int NT = N / 4;
  constexpr int NH = N / 2;
  __shared__ __align__(16) float2 sbuf[2][N];
  const int tid = threadIdx.x;
  const int kx = blockIdx.x;   // 0..N/2 inclusive
  const int img = blockIdx.y;
  float2* rowp = inout + ((size_t)img * PITCH + kx) * N;

#pragma unroll
  for (int i = tid; i < N; i += NT)
    sbuf[0][i] = rowp[i];
  __syncthreads();

  int cur = fft_core4<N>(sbuf, -1.0f, tid, 0);

  const float pr = g_phi[phi_off(N) + kx];
  const float inv = 1.0f / (float)N;
  float2* fp = foldb + ((size_t)img * (NH + 1) + kx) * NH;
#pragma unroll
  for (int i = tid; i < NH; i += NT) {
    float2 vA = sbuf[cur][i];
    float2 vB = sbuf[cur][i + NH];
    float lmA = pr * g_phi[phi_off(N) + i];
    float lmB = pr * g_phi[phi_off(N) + i + NH];
    fp[i] = make_float2(0.25f * (vA.x * lmA + vB.x * lmB),
                        0.25f * (vA.y * lmA + vB.y * lmB));
    float hmA = sqrtf(fmaxf(1.0f - lmA * lmA, 0.0f)) * inv;
    float hmB = sqrtf(fmaxf(1.0f - lmB * lmB, 0.0f)) * inv;
    sbuf[cur][i]      = make_float2(vA.x * hmA, vA.y * hmA);
    sbuf[cur][i + NH] = make_float2(vB.x * hmB, vB.y * hmB);
  }
  __syncthreads();

  cur = fft_core4<N>(sbuf, 1.0f, tid, cur);

#pragma unroll
  for (int i = tid; i < N; i += NT)
    rowp[i] = sbuf[cur][i];
}

// kx-fold from the half-spectrum fold buffer:
// spec2[r][c] = fold[r][c] + conj(fold[512-r][(512-c) mod 512])
__global__ void fold_combine_k(const float2* __restrict__ fold,
                               float2* __restrict__ spec2) {
  int idx = blockIdx.x * 256 + threadIdx.x;
  int c = idx & 511;
  int r = (idx >> 9) & 511;
  int img = idx >> 18;
  const float2* fb = fold + (size_t)img * (513 * 512);
  float2 a = fb[(size_t)r * 512 + c];
  float2 b = fb[(size_t)(512 - r) * 512 + ((512 - c) & 511)];
  spec2[((size_t)img << 18) + ((size_t)r << 9) + c] =
      make_float2(a.x + b.x, a.y - b.y);
}

// ---------------------------------------------------------------------------
// Level-1 fused inverse row FFT + first DFB fan split, TWO ROWS PER BLOCK:
// rows of Z over kx are conjugate-symmetric, so rows y0=2q (re) and y1=2q+1
// (im) are packed into one complex inverse FFT from the stored half-spectrum.
// ---------------------------------------------------------------------------
template <int N, int PITCH>
__global__ void __launch_bounds__(N / 4)
ifft_fan_pair_k(const float2* __restrict__ in, float* __restrict__ outb,
                float scale, int halfT) {
  constexpr int NT = N / 4;
  constexpr int W2 = N / 2;
  __shared__ __align__(16) float2 sbuf[2][N];
  const int tid = threadIdx.x;
  const int img = blockIdx.x >> (ilog2c(N) - 1);
  const int q = blockIdx.x & (N / 2 - 1);
  const int y0 = 2 * q;
  const float2* inA = in + ((size_t)img * N + y0) * PITCH;
  const float2* inB = inA + PITCH;

#pragma unroll
  for (int i = tid; i <= W2; i += NT) {
    float2 a = inA[i], b = inB[i];
    sbuf[0][i] = make_float2((a.x - b.y) * scale, (a.y + b.x) * scale);
  }
#pragma unroll
  for (int i = tid; i < W2 - 1; i += NT) {
    int m = W2 - 1 - i;                  // source index: 511..1
    float2 a = inA[m], b = inB[m];
    sbuf[0][W2 + 1 + i] = make_float2((a.x + b.y) * scale, (b.x - a.y) * scale);
  }
  __syncthreads();

  int cur = fft_core4<N>(sbuf, 1.0f, tid, 0);

  float* scratch = (float*)sbuf[cur ^ 1];
  float* xe = scratch;            // W2 floats
  float* xo = scratch + W2;       // W2 floats
  float* db = scratch + 2 * W2;   // W2 floats
  const size_t rbase = ((size_t)img * N + y0) * W2;

  for (int sub = 0; sub < 2; ++sub) {
    const int par = sub;                 // y0 even, y1 odd
    const float sgn = par ? -1.0f : 1.0f;
#pragma unroll
    for (int i = tid; i < N; i += NT) {
      float v = par ? sbuf[cur][i].y : sbuf[cur][i].x;
      int ii = (i - par) & (N - 1);
      if (ii & 1) xo[ii >> 1] = v; else xe[ii >> 1] = v;
    }
    __syncthreads();

    float* outs = outb + rbase + (size_t)sub * W2;
    float* outd = outb + halfT + rbase + (size_t)sub * W2;
#pragma unroll 2
    for (int j = tid; j < W2; j += NT) {
      float acc = 0.0f;
#pragma unroll
      for (int k = 0; k < 12; k++)
        acc += c_pkva[k] * xe[(j - 6 + k + W2) & (W2 - 1)];
      float dv = sgn * (xo[j] - acc);
      db[j] = dv;
      outd[j] = dv;
    }
    __syncthreads();
#pragma unroll 2
    for (int j = tid; j < W2; j += NT) {
      float acc = 0.0f;
#pragma unroll
      for (int k = 0; k < 12; k++)
        acc += c_pkva[k] * db[(j - 6 + k + W2) & (W2 - 1)];
      outs[j] = sgn * xe[j] + 0.5f * acc;
    }
    __syncthreads();
  }
}

// ---------------------------------------------------------------------------
// Fused: inverse row FFT + first DFB fan split (axis=-1). Used at levels 2/3.
// ---------------------------------------------------------------------------
template <int N>
__global__ void __launch_bounds__(N / 4)
ifft_fan_k(const float2* __restrict__ in, float* __restrict__ outb,
           float scale, int halfT) {
  constexpr int NT = N / 4;
  constexpr int W2 = N / 2;
  __shared__ __align__(16) float2 sbuf[2][N];
  const int tid = threadIdx.x;
  const int nr = blockIdx.x;
  const int r = nr & (N - 1);
  const int par = r & 1;
  const float sgn = par ? -1.0f : 1.0f;

#pragma unroll
  for (int i = tid; i < N; i += NT) {
    float2 v = in[(size_t)nr * N + i];
    sbuf[0][i] = make_float2(v.x * scale, v.y * scale);
  }
  __syncthreads();

  int cur = fft_core4<N>(sbuf, 1.0f, tid, 0);

  float* scratch = (float*)sbuf[cur ^ 1];
  float* xe = scratch;            // W2 floats
  float* xo = scratch + W2;       // W2 floats
  float* db = scratch + 2 * W2;   // W2 floats
#pragma unroll
  for (int i = tid; i < N; i += NT) {
    float v = sbuf[cur][i].x;
    int ii = (i - par) & (N - 1);
    if (ii & 1) xo[ii >> 1] = v; else xe[ii >> 1] = v;
  }
  __syncthreads();

  float* outs = outb + (size_t)nr * W2;
  float* outd = outb + halfT + (size_t)nr * W2;
#pragma unroll 2
  for (int j = tid; j < W2; j += NT) {
    float acc = 0.0f;
#pragma unroll
    for (int k = 0; k < 12; k++)
      acc += c_pkva[k] * xe[(j - 6 + k + W2) & (W2 - 1)];
    float dv = sgn * (xo[j] - acc);
    db[j] = dv;
    outd[j] = dv;
  }
  __syncthreads();
#pragma unroll 2
  for (int j = tid; j < W2; j += NT) {
    float acc = 0.0f;
#pragma unroll
    for (int k = 0; k < 12; k++)
      acc += c_pkva[k] * db[(j - 6 + k + W2) & (W2 - 1)];
    outs[j] = sgn * xe[j] + 0.5f * acc;
  }
}

// Batched square transpose (per-image), complex
__global__ void transpose_k(const float2* __restrict__ in,
                            float2* __restrict__ out, int N) {
  __shared__ float2 tile[32][33];
  int img = blockIdx.z;
  size_t base = (size_t)img * N * N;
  int x = blockIdx.x * 32 + threadIdx.x;
  int y0 = blockIdx.y * 32;
  for (int j = threadIdx.y; j < 32; j += 8)
    tile[j][threadIdx.x] = in[base + (size_t)(y0 + j) * N + x];
  __syncthreads();
  int x2 = blockIdx.y * 32 + threadIdx.x;
  int y2 = blockIdx.x * 32;
  for (int j = threadIdx.y; j < 32; j += 8)
    out[base + (size_t)(y2 + j) * N + x2] = tile[threadIdx.x][j];
}

// Frequency-domain decimation by 2 with Lm mask (levels 2/3), table-driven.
__global__ void alias_k(const float2* __restrict__ in, float2* __restrict__ out,
                        int N, int lgN2, int phiOff) {
  int idx = blockIdx.x * 256 + threadIdx.x;
  int N2 = N >> 1;
  int c = idx & (N2 - 1);
  int r = (idx >> lgN2) & (N2 - 1);
  int img = idx >> (2 * lgN2);
  float pr0 = g_phi[phiOff + r], pr1 = g_phi[phiOff + r + N2];
  float pc0 = g_phi[phiOff + c], pc1 = g_phi[phiOff + c + N2];
  size_t base = (size_t)img * N * N;
  float2 v00 = in[base + (size_t)r * N + c];
  float2 v01 = in[base + (size_t)r * N + c + N2];
  float2 v10 = in[base + (size_t)(r + N2) * N + c];
  float2 v11 = in[base + (size_t)(r + N2) * N + c + N2];
  float m00 = pr0 * pc0, m01 = pr0 * pc1, m10 = pr1 * pc0, m11 = pr1 * pc1;
  float2 o;
  o.x = 0.25f * (v00.x * m00 + v01.x * m01 + v10.x * m10 + v11.x * m11);
  o.y = 0.25f * (v00.y * m00 + v01.y * m01 + v10.y * m10 + v11.y * m11);
  out[((size_t)img << (2 * lgN2)) + ((size_t)r << lgN2) + c] = o;
}

// Standalone DFB fan split, axis=-1 (mid-pipeline; W <= 512 here).
__global__ void __launch_bounds__(256)
fs_row_k(const float* __restrict__ x, float* __restrict__ outb,
         int lgH, int lgW, int halfT) {
  __shared__ float xe[512], xo[512], db[512];
  int H = 1 << lgH, W = 1 << lgW, W2 = W >> 1;
  int nr = blockIdx.x;
  int r = nr & (H - 1);
  int par = r & 1;
  float sgn = par ? -1.0f : 1.0f;
  const float* xrow = x + (size_t)nr * W;
  for (int j = threadIdx.x; j < W2; j += 256) {
    xe[j] = sgn * xrow[(2 * j + par) & (W - 1)];
    xo[j] = sgn * xrow[(2 * j + 1 + par) & (W - 1)];
  }
  __syncthreads();
  float* outs = outb + (size_t)nr * W2;
  float* outd = outb + halfT + (size_t)nr * W2;
  for (int j = threadIdx.x; j < W2; j += 256) {
    float acc = 0.0f;
#pragma unroll
    for (int k = 0; k < 12; k++)
      acc += c_pkva[k] * xe[(j - 6 + k + W2) & (W2 - 1)];
    float dv = xo[j] - acc;
    db[j] = dv;
    outd[j] = dv;
  }
  __syncthreads();
  for (int j = threadIdx.x; j < W2; j += 256) {
    float acc = 0.0f;
#pragma unroll
    for (int k = 0; k < 12; k++)
      acc += c_pkva[k] * db[(j - 6 + k + W2) & (W2 - 1)];
    outs[j] = xe[j] + 0.5f * acc;
  }
}

// ---------------------------------------------------------------------------
// FUSED column fan split (d AND s in one pass, input read once).
// Tile: TI output rows x TC columns per block. Raw rows (both parities, with
// full tap halo) staged in LDS; unsigned detail dv computed on the extended
// range [i0-6, i0+TI+6) in LDS; both outputs written from registers.
// Circularity: 2*(m mod H2) + par == (2m+par) mod H, so raw-row wrap via
// &(H-1) is exact.  d[i] = sgn*dv[i];  s[i] = sgn*(p0[i] + 0.5*conv(dv)).
// Bank layout raw[r][tc]: bank = tc -> conflict-free (2 lanes/bank, free).
// ---------------------------------------------------------------------------
template <int TI, int TC>
__global__ void __launch_bounds__(256)
fs_col_fused_k(const float* __restrict__ x, float* __restrict__ outb,
               int lgH, int lgW, int halfT) {
  constexpr int RE = 2 * TI + 48;   // raw halo rows (needs 2*TI+46)
  constexpr int DE = TI + 12;       // extended dv rows
  constexpr int NR = 256 / TC;
  __shared__ float raw[RE][TC];
  __shared__ float dvs[DE][TC];
  const int H = 1 << lgH, W = 1 << lgW;
  const int c0 = blockIdx.x * TC;
  const int i0 = blockIdx.y * TI;
  const int n = blockIdx.z;
  const int tc = threadIdx.x & (TC - 1);
  const int tr = threadIdx.x / TC;
  const float* xim = x + ((size_t)n << (lgH + lgW));
  const int rbase = 2 * i0 - 24;
#pragma unroll
  for (int r = tr; r < RE; r += NR) {
    int rr = (rbase + r) & (H - 1);
    raw[r][tc] = xim[((size_t)rr << lgW) + c0 + tc];
  }
  __syncthreads();
  const int par = tc & 1;  // c0 is a multiple of TC (even)
  for (int j = tr; j < DE; j += NR) {
    // absolute output index a = i0 - 6 + j
    // p0[a-6+k] raw offset = 2j + 2k + par ; p1[a] raw offset = 2j + 13 + par
    float acc = 0.0f;
#pragma unroll
    for (int k = 0; k < 12; k++)
      acc += c_pkva[k] * raw[2 * j + 2 * k + par][tc];
    dvs[j][tc] = raw[2 * j + 13 + par][tc] - acc;
  }
  __syncthreads();
  const float sgn = par ? -1.0f : 1.0f;
  float* outs = outb + (((size_t)n << (lgH - 1)) << lgW);
  float* outd = outs + halfT;
  for (int i = tr; i < TI; i += NR) {
    float acc = 0.0f;
#pragma unroll
    for (int k = 0; k < 12; k++)
      acc += c_pkva[k] * dvs[i + k][tc];
    float p0v = raw[2 * i + 24 + par][tc];     // p0[i0+i]
    size_t off = ((size_t)(i0 + i) << lgW) + c0 + tc;
    outd[off] = sgn * dvs[i + 6][tc];
    outs[off] = sgn * (p0v + 0.5f * acc);
  }
}

__global__ void fill_err_k(float* out) {
  out[threadIdx.x] = 1.0e9f;
}

// ---------------------------------------------------------------------------
extern "C" void kernel_launch(void* const* d_in, const int* in_sizes, int n_in,
                              void* d_out, int out_size, void* d_ws, size_t ws_size,
                              hipStream_t stream) {
  const float* x = (const float*)d_in[0];
  float* out = (float*)d_out;
  char* ws = (char*)d_ws;

  const size_t NEED = 220266496ull;
  if (ws_size < NEED) {
    fill_err_k<<<dim3(1), dim3(256), 0, stream>>>(out);
    return;
  }

  float2* bufA  = (float2*)(ws);                 // 16*1024*544*8 = 71303168
  float2* bufB  = (float2*)(ws + 71303168);      // 71303168
  float2* foldb = (float2*)(ws + 142606336);     // 16*513*512*8 = 33619968
  float2* spec2 = (float2*)(ws + 176226304);     // 33554432
  float2* spec3 = (float2*)(ws + 209780736);     // 8388608
  float2* spec4 = (float2*)(ws + 218169344);     // 2097152

  float* out0 = out;             // 262144
  float* out1 = out + 262144;    // 1048576
  float* out2 = out + 1310720;   // 4194304
  float* out3 = out + 5505024;   // 16777216

  phi_init_k<<<dim3(8), dim3(256), 0, stream>>>();

  // ---- Level 1 (half-spectrum in kx)
  rfft_pairs_half_k<1024, 544><<<dim3(8192), dim3(256), 0, stream>>>(x, bufA);
  transpose_rect_k<<<dim3(17, 32, 16), dim3(32, 8), 0, stream>>>(bufA, bufB, 1024, 544);
  fft_col_half_k<1024, 544><<<dim3(513, 16), dim3(256), 0, stream>>>(bufB, foldb);
  fold_combine_k<<<dim3(16384), dim3(256), 0, stream>>>(foldb, spec2);
  transpose_rect_k<<<dim3(32, 17, 16), dim3(32, 8), 0, stream>>>(bufB, bufA, 544, 1024);
  ifft_fan_pair_k<1024, 544><<<dim3(8192), dim3(256), 0, stream>>>(bufA, (float*)bufB, 1.0f / 1024.0f, 8388608);
  // DFB n=4 remaining stages (fused column splits)
  fs_col_fused_k<64, 32><<<dim3(16, 8, 32), dim3(256), 0, stream>>>((float*)bufB, (float*)bufA, 10, 9, 8388608);
  fs_row_k<<<dim3(32768), dim3(256), 0, stream>>>((float*)bufA, (float*)bufB, 9, 9, 8388608);
  fs_col_fused_k<64, 32><<<dim3(8, 4, 128), dim3(256), 0, stream>>>((float*)bufB, out3, 9, 8, 8388608);

  // ---- Level 2
  alias_k<<<dim3(4096), dim3(256), 0, stream>>>(spec2, spec3, 512, 8, phi_off(512));
  fft_rows_k<512, 2, 0><<<dim3(8192), dim3(128), 0, stream>>>((const void*)spec2, (void*)bufA, 1.0f, 1.0f / 512.0f);
  transpose_k<<<dim3(16, 16, 16), dim3(32, 8), 0, stream>>>(bufA, bufB, 512);
  ifft_fan_k<512><<<dim3(8192), dim3(128), 0, stream>>>(bufB, (float*)bufA, 1.0f / 512.0f, 2097152);
  fs_col_fused_k<64, 32><<<dim3(8, 4, 32), dim3(256), 0, stream>>>((float*)bufA, (float*)bufB, 9, 8, 2097152);
  fs_row_k<<<dim3(16384), dim3(256), 0, stream>>>((float*)bufB, out2, 8, 8, 2097152);

  // ---- Level 3
  alias_k<<<dim3(1024), dim3(256), 0, stream>>>(spec3, spec4, 256, 7, phi_off(256));
  fft_rows_k<256, 2, 0><<<dim3(4096), dim3(64), 0, stream>>>((const void*)spec3, (void*)bufA, 1.0f, 1.0f / 256.0f);
  transpose_k<<<dim3(8, 8, 16), dim3(32, 8), 0, stream>>>(bufA, bufB, 256);
  ifft_fan_k<256><<<dim3(4096), dim3(64), 0, stream>>>(bufB, (float*)bufA, 1.0f / 256.0f, 524288);
  fs_col_fused_k<64, 32><<<dim3(4, 2, 32), dim3(256), 0, stream>>>((float*)bufA, out1, 8, 7, 524288);

  // ---- Final lowpass: out0 = ifft2(X4^T) at 128^2
  fft_rows_k<128, 1, 0><<<dim3(2048), dim3(32), 0, stream>>>((const void*)spec4, (void*)bufA, 1.0f, 1.0f / 128.0f);
  transpose_k<<<dim3(4, 4, 16), dim3(32, 8), 0, stream>>>(bufA, bufB, 128);
  fft_rows_k<128, 1, 1><<<dim3(2048), dim3(32), 0, stream>>>((const void*)bufB, (void*)out0, 1.0f, 1.0f / 128.0f);
}